// Round 9
// baseline (96.326 us; speedup 1.0000x reference)
//
#include <hip/hip_runtime.h>
#include <math.h>

#define HH 256
#define WW 256
#define CC 8
#define KK 25
#define ND 9
#define NB 2
#define HW (HH * WW)

typedef int   int4v   __attribute__((ext_vector_type(4)));
typedef float float2v __attribute__((ext_vector_type(2)));

// Raw buffer loads: per-dword hardware bounds check vs num_records; negative
// voffset = huge unsigned = OOB -> returns 0 (validated round 8, absmax 0.0).
__device__ float llvm_amdgcn_raw_buffer_load_fp32(int4v srsrc, int voffset,
                                                  int soffset, int aux)
    __asm("llvm.amdgcn.raw.buffer.load.f32");
__device__ float2v llvm_amdgcn_raw_buffer_load_v2fp32(int4v srsrc, int voffset,
                                                      int soffset, int aux)
    __asm("llvm.amdgcn.raw.buffer.load.v2f32");

__global__ __launch_bounds__(256) void cost_kernel(
    const float* __restrict__ fm,    // [B][C][K][H][W]
    const float* __restrict__ mask,  // [B][K][H][W]
    const float* __restrict__ wgt,   // [C][K]
    float* __restrict__ out)         // [B][C][ND][H][W]
{
#pragma clang fp contract(off)
    const int tid = threadIdx.x;
    const int jj  = (tid & 127) << 1;     // column pair start (wave-contiguous)
    const int rr  = tid >> 7;             // row within block (0..1)

    // XCD-chunked swizzle over 2048 row-pair blocks (kept from round 8).
    const int vb  = blockIdx.x;
    const int nid = (vb & 7) * (NB * CC * HH / 2 / 8) + (vb >> 3);
    const int i = ((nid & 127) << 1) + rr;   // row (uniform per wave)
    const int c = (nid >> 7) & 7;            // channel
    const int b = nid >> 10;                 // batch

    const float* fmb   = fm + (size_t)(b * CC + c) * KK * HW;
    const float* mbase = mask + (size_t)b * KK * HW + (size_t)i * WW + jj;
    const float* wc    = wgt + c * KK;

    // 17 byte-voffsets: entry s -> column jj + (s-8). Statically indexed only.
    int voff[17];
#pragma unroll
    for (int s = 0; s < 17; ++s) voff[s] = (jj + (s - 8)) * 4;

    float acc0[ND], acc1[ND];
#pragma unroll
    for (int dd = 0; dd < ND; ++dd) { acc0[dd] = 0.f; acc1[dd] = 0.f; }
    float msum0 = 0.f, msum1 = 0.f;

    // k = 5*g + v ascending (strict numpy order, per-pixel chain unchanged).
    for (int g = 0; g < 5; ++g) {
        const int du = g - 2;
#pragma unroll
        for (int v = 0; v < 5; ++v) {
            const int k  = 5 * g + v;
            const int dv = v - 2;
            const float2v mk = *(const float2v*)(mbase + (size_t)k * HW);
            const float wk = wc[k];
            const float* fpk = fmb + (size_t)k * HW;
            msum0 = __fadd_rn(msum0, mk.x);
            msum1 = __fadd_rn(msum1, mk.y);

            float f0[ND], f1[ND];
#pragma unroll
            for (int dd = 0; dd < ND; ++dd) {
                const int d  = dd - 4;
                const int y  = i - du * d;                 // uniform
                const int yv = ((unsigned)y < HH);
                const int yc = min(max(y, 0), HH - 1);
                const float* rowp = fpk + yc * WW;         // uniform -> SGPRs
                int4v srd;
                srd.x = (int)(uintptr_t)rowp;
                srd.y = (int)((uintptr_t)rowp >> 32);
                srd.z = yv ? (WW * 4) : 0;                 // 0 => whole row -> 0
                srd.w = 0x00020000;
                const int sp = -dv * d;                    // col shift, literal
                const int si = sp + 8;
                if ((sp & 1) == 0) {
                    // even shift: pair is fully in-bounds or fully OOB -> 1 load
                    const float2v fv =
                        llvm_amdgcn_raw_buffer_load_v2fp32(srd, voff[si], 0, 0);
                    f0[dd] = fv.x; f1[dd] = fv.y;
                } else {
                    // odd shift (dv odd && d odd): per-dword exact OOB
                    f0[dd] = llvm_amdgcn_raw_buffer_load_fp32(srd, voff[si], 0, 0);
                    f1[dd] = llvm_amdgcn_raw_buffer_load_fp32(srd, voff[si + 1], 0, 0);
                }
            }
#pragma unroll
            for (int dd = 0; dd < ND; ++dd) {
                const float p0 = __fmul_rn(f0[dd], mk.x);
                const float t0 = __fmul_rn(p0, wk);
                acc0[dd] = __fadd_rn(acc0[dd], t0);
                const float p1 = __fmul_rn(f1[dd], mk.y);
                const float t1 = __fmul_rn(p1, wk);
                acc1[dd] = __fadd_rn(acc1[dd], t1);
            }
        }
    }

    const float mavg0 = __fdiv_rn(msum0, 25.0f);
    const float mavg1 = __fdiv_rn(msum1, 25.0f);
    float* ob = out + (size_t)(b * CC + c) * ND * HW + (size_t)i * WW + jj;
#pragma unroll
    for (int dd = 0; dd < ND; ++dd) {
        float2v o;
        o.x = floorf(__fdiv_rn(acc0[dd], mavg0));
        o.y = floorf(__fdiv_rn(acc1[dd], mavg1));
        *(float2v*)(ob + (size_t)dd * HW) = o;
    }
}

extern "C" void kernel_launch(void* const* d_in, const int* in_sizes, int n_in,
                              void* d_out, int out_size, void* d_ws, size_t ws_size,
                              hipStream_t stream) {
    const float* fm   = (const float*)d_in[0];
    const float* mask = (const float*)d_in[1];
    const float* wgt  = (const float*)d_in[2];
    float* out = (float*)d_out;

    dim3 grid(NB * CC * HH / 2);  // 2048 blocks: (b, c, row pair), XCD-swizzled
    dim3 block(256);              // 2 rows x 128 threads x 2 px
    cost_kernel<<<grid, block, 0, stream>>>(fm, mask, wgt, out);
}

// Round 10
// 53.372 us; speedup vs baseline: 1.8048x; 1.8048x over previous
//
#include <hip/hip_runtime.h>
#include <math.h>

#define HH 256
#define WW 256
#define CC 8
#define KK 25
#define ND 9
#define NB 2
#define HW (HH * WW)

typedef int int4v __attribute__((ext_vector_type(4)));

// Raw buffer load: per-dword hardware bounds check vs num_records; negative
// voffset = huge unsigned = OOB -> returns 0 (validated rounds 8/9, absmax 0.0).
__device__ float llvm_amdgcn_raw_buffer_load_fp32(int4v srsrc, int voffset,
                                                  int soffset, int aux)
    __asm("llvm.amdgcn.raw.buffer.load.f32");

__global__ __launch_bounds__(256, 4) void cost_kernel(
    const float* __restrict__ fm,    // [B][C][K][H][W]
    const float* __restrict__ mask,  // [B][K][H][W]
    const float* __restrict__ wgt,   // [C][K]
    float* __restrict__ out)         // [B][C][ND][H][W]
{
#pragma clang fp contract(off)
    const int j = threadIdx.x;            // column; wave = 64 consecutive cols

    // XCD-chunked swizzle (round 8): each XCD owns a contiguous id range.
    const int vb = blockIdx.x;
    const int nid = (vb & 7) * (NB * CC * HH / 8) + (vb >> 3);
    const int i = nid & 255;              // row (uniform)
    const int c = (nid >> 8) & 7;         // channel
    const int b = nid >> 11;              // batch

    const float* fmb = fm + (size_t)(b * CC + c) * KK * HW;
    const float* mb  = mask + (size_t)b * KK * HW + (size_t)i * WW + j;
    const float* wc  = wgt + c * KK;

    // 17 per-lane byte voffsets: entry s -> column j + (s-8); negative -> HW 0.
    int voff[17];
#pragma unroll
    for (int s = 0; s < 17; ++s) voff[s] = (j + (s - 8)) * 4;

    float acc[ND];
#pragma unroll
    for (int dd = 0; dd < ND; ++dd) acc[dd] = 0.f;
    float msum = 0.f;

    // k = 5*g + v ascending (strict numpy order). Per (g,v): batch-issue all
    // 9 buffer_loads into f[] (independent dest regs -> 9 in flight), THEN the
    // dependent FP chain. launch_bounds(256,4) gives the regalloc room for it.
    for (int g = 0; g < 5; ++g) {
        const int du = g - 2;
#pragma unroll
        for (int v = 0; v < 5; ++v) {
            const int k  = 5 * g + v;
            const int dv = v - 2;
            const float mk = mb[(size_t)k * HW];
            const float wk = wc[k];
            const float* fpk = fmb + (size_t)k * HW;

            float f[ND];                       // batch of 9 independent loads
#pragma unroll
            for (int dd = 0; dd < ND; ++dd) {
                const int d  = dd - 4;
                const int y  = i - du * d;                // uniform
                const int yv = ((unsigned)y < HH);
                const int yc = min(max(y, 0), HH - 1);
                const float* rowp = fpk + yc * WW;        // uniform -> SGPRs
                int4v srd;
                srd.x = (int)(uintptr_t)rowp;
                srd.y = (int)((uintptr_t)rowp >> 32);
                srd.z = yv ? (WW * 4) : 0;                // 0 => whole row -> 0
                srd.w = 0x00020000;
                const int s = 8 - dv * d;                 // literal table index
                f[dd] = llvm_amdgcn_raw_buffer_load_fp32(srd, voff[s], 0, 0);
            }
            msum = __fadd_rn(msum, mk);
#pragma unroll
            for (int dd = 0; dd < ND; ++dd) {
                const float p = __fmul_rn(f[dd], mk);     // shifted * mask
                const float t = __fmul_rn(p, wk);         // * weight
                acc[dd] = __fadd_rn(acc[dd], t);          // sequential k-sum
            }
        }
    }

    const float mavg = __fdiv_rn(msum, 25.0f);
    float* ob = out + (size_t)(b * CC + c) * ND * HW + (size_t)i * WW + j;
#pragma unroll
    for (int dd = 0; dd < ND; ++dd)
        ob[(size_t)dd * HW] = floorf(__fdiv_rn(acc[dd], mavg));
}

extern "C" void kernel_launch(void* const* d_in, const int* in_sizes, int n_in,
                              void* d_out, int out_size, void* d_ws, size_t ws_size,
                              hipStream_t stream) {
    const float* fm   = (const float*)d_in[0];
    const float* mask = (const float*)d_in[1];
    const float* wgt  = (const float*)d_in[2];
    float* out = (float*)d_out;

    dim3 grid(NB * CC * HH);   // 4096 blocks: (b, c, row), XCD-swizzled
    dim3 block(WW);            // 256 threads: 1 column each
    cost_kernel<<<grid, block, 0, stream>>>(fm, mask, wgt, out);
}

// Round 11
// 51.672 us; speedup vs baseline: 1.8642x; 1.0329x over previous
//
#include <hip/hip_runtime.h>
#include <math.h>

#define HH 256
#define WW 256
#define CC 8
#define KK 25
#define ND 9
#define NB 2
#define HW (HH * WW)

typedef int int4v __attribute__((ext_vector_type(4)));

// Raw buffer load: per-dword hardware bounds check vs num_records; negative
// voffset = huge unsigned = OOB -> returns 0 (validated rounds 8-10, absmax 0.0).
__device__ float llvm_amdgcn_raw_buffer_load_fp32(int4v srsrc, int voffset,
                                                  int soffset, int aux)
    __asm("llvm.amdgcn.raw.buffer.load.f32");

// Issue the 10 loads (9 fm taps + 1 mask) of tap-group (g, VV). VV is a
// template arg so every voff[] index is a compile-time literal (stays in VGPRs).
template<int VV>
__device__ __forceinline__ void load_group(int g, int du, int i,
    const float* __restrict__ fmb, const float* __restrict__ mb,
    const int (&voff)[17], float (&F)[ND], float& MK)
{
    const int k = 5 * g + VV;
    constexpr int dv = VV - 2;
    MK = mb[(size_t)k * HW];
    const float* fpk = fmb + (size_t)k * HW;
#pragma unroll
    for (int dd = 0; dd < ND; ++dd) {
        const int d  = dd - 4;                      // literal (unrolled)
        const int y  = i - du * d;                  // uniform
        const int yv = ((unsigned)y < HH);
        const int yc = min(max(y, 0), HH - 1);
        const float* rowp = fpk + yc * WW;          // uniform -> SGPRs
        int4v srd;
        srd.x = (int)(uintptr_t)rowp;
        srd.y = (int)((uintptr_t)rowp >> 32);
        srd.z = yv ? (WW * 4) : 0;                  // 0 => whole row OOB -> 0
        srd.w = 0x00020000;
        F[dd] = llvm_amdgcn_raw_buffer_load_fp32(srd, voff[8 - dv * d], 0, 0);
    }
}

// Consume group (g, VV): strict numpy chain, k ascending overall.
template<int VV>
__device__ __forceinline__ void consume_group(int g,
    const float* __restrict__ wc, const float (&F)[ND], float MK,
    float& msum, float (&acc)[ND])
{
    msum = __fadd_rn(msum, MK);
    const float wk = wc[5 * g + VV];
#pragma unroll
    for (int dd = 0; dd < ND; ++dd) {
        const float p = __fmul_rn(F[dd], MK);       // shifted * mask
        const float t = __fmul_rn(p, wk);           // * weight
        acc[dd] = __fadd_rn(acc[dd], t);            // sequential k-sum
    }
}

__global__ __launch_bounds__(256, 4) void cost_kernel(
    const float* __restrict__ fm,    // [B][C][K][H][W]
    const float* __restrict__ mask,  // [B][K][H][W]
    const float* __restrict__ wgt,   // [C][K]
    float* __restrict__ out)         // [B][C][ND][H][W]
{
#pragma clang fp contract(off)
    const int j = threadIdx.x;            // column; wave = 64 consecutive cols

    // XCD-chunked swizzle (round 8): each XCD owns a contiguous id range.
    const int vb = blockIdx.x;
    const int nid = (vb & 7) * (NB * CC * HH / 8) + (vb >> 3);
    const int i = nid & 255;              // row (uniform)
    const int c = (nid >> 8) & 7;         // channel
    const int b = nid >> 11;              // batch

    const float* fmb = fm + (size_t)(b * CC + c) * KK * HW;
    const float* mb  = mask + (size_t)b * KK * HW + (size_t)i * WW + j;
    const float* wc  = wgt + c * KK;

    // 17 per-lane byte voffsets: entry s -> column j + (s-8); negative -> HW 0.
    int voff[17];
#pragma unroll
    for (int s = 0; s < 17; ++s) voff[s] = (j + (s - 8)) * 4;

    float acc[ND];
#pragma unroll
    for (int dd = 0; dd < ND; ++dd) acc[dd] = 0.f;
    float msum = 0.f;

    // 2-deep software pipeline over the 5 v-groups of each g: group v+1's
    // 10 loads are in flight while group v is consumed (~20 outstanding).
    for (int g = 0; g < 5; ++g) {
        const int du = g - 2;
        float fA[ND], fB[ND];
        float mkA, mkB;
        load_group<0>(g, du, i, fmb, mb, voff, fA, mkA);
        load_group<1>(g, du, i, fmb, mb, voff, fB, mkB);
        consume_group<0>(g, wc, fA, mkA, msum, acc);
        load_group<2>(g, du, i, fmb, mb, voff, fA, mkA);
        consume_group<1>(g, wc, fB, mkB, msum, acc);
        load_group<3>(g, du, i, fmb, mb, voff, fB, mkB);
        consume_group<2>(g, wc, fA, mkA, msum, acc);
        load_group<4>(g, du, i, fmb, mb, voff, fA, mkA);
        consume_group<3>(g, wc, fB, mkB, msum, acc);
        consume_group<4>(g, wc, fA, mkA, msum, acc);
    }

    const float mavg = __fdiv_rn(msum, 25.0f);
    float* ob = out + (size_t)(b * CC + c) * ND * HW + (size_t)i * WW + j;
#pragma unroll
    for (int dd = 0; dd < ND; ++dd)
        ob[(size_t)dd * HW] = floorf(__fdiv_rn(acc[dd], mavg));
}

extern "C" void kernel_launch(void* const* d_in, const int* in_sizes, int n_in,
                              void* d_out, int out_size, void* d_ws, size_t ws_size,
                              hipStream_t stream) {
    const float* fm   = (const float*)d_in[0];
    const float* mask = (const float*)d_in[1];
    const float* wgt  = (const float*)d_in[2];
    float* out = (float*)d_out;

    dim3 grid(NB * CC * HH);   // 4096 blocks: (b, c, row), XCD-swizzled
    dim3 block(WW);            // 256 threads: 1 column each
    cost_kernel<<<grid, block, 0, stream>>>(fm, mask, wgt, out);
}